// Round 6
// baseline (770.501 us; speedup 1.0000x reference)
//
#include <hip/hip_runtime.h>

typedef short short8 __attribute__((ext_vector_type(8)));
typedef float f32x4 __attribute__((ext_vector_type(4)));

#define N_NODES   100000
#define E_KEEP    1000000
#define E_TOTAL_N 1100000
#define EDGE_OUT_BASE 12800000L

__device__ __forceinline__ unsigned short f2bf(float f) {
  unsigned int u = __builtin_bit_cast(unsigned int, f);
  u += 0x7fffu + ((u >> 16) & 1u);   // round-to-nearest-even
  return (unsigned short)(u >> 16);
}

// relu + pack 8 f32 -> short8 bf16 (k-order: h0[0..3], h1[0..3]) — R2-proven.
__device__ __forceinline__ short8 mk_hfrag(f32x4 h0, f32x4 h1) {
  short8 hf;
#pragma unroll
  for (int j = 0; j < 4; ++j) hf[j]     = (short)f2bf(fmaxf(h0[j], 0.f));
#pragma unroll
  for (int j = 0; j < 4; ++j) hf[4 + j] = (short)f2bf(fmaxf(h1[j], 0.f));
  return hf;
}

// nw2/ew2 fp32 [128][128] -> bf16 W2^T in ws (node [0:16384], edge [16384:32768])
__global__ void transpose_w2(const float* __restrict__ nw2,
                             const float* __restrict__ ew2,
                             unsigned short* __restrict__ ws) {
  int idx = blockIdx.x * 256 + threadIdx.x;
  for (int i = idx; i < 32768; i += 8192) {
    int m = i >> 14;
    int w = i & 16383;
    int k = w >> 7;
    int n = w & 127;
    const float* src = m ? ew2 : nw2;
    ws[m * 16384 + n * 128 + k] = f2bf(src[w]);  // W2T[n][k] = W2[k][n]
  }
}

// 512 threads = 8 waves = 2 row-groups (rg) x 4 col-groups (wc, 32 cols each).
// Per wave: 16 rows x 32 cols -> wfrag[2][4] = 32 VGPR, acc = 8 VGPR.
// Low VGPR => 4 waves/SIMD for latency hiding (the R2/R5 bottleneck).

// ---------------- edge path: attr = [dx, dy, norm], K1 = 3 ----------------
__device__ __forceinline__ void run_edges(
    const float* __restrict__ pos,
    const int* __restrict__ ei,
    const float* __restrict__ w1,
    const float* __restrict__ b1,
    const float* __restrict__ b2,
    const unsigned short* __restrict__ w2t,
    float* __restrict__ outp,
    int bid)
{
  __shared__ float w1f[3 * 128];
  __shared__ float b1f[128];
  __shared__ float b2f[128];
  int t = threadIdx.x;
  if (t < 128) { b1f[t] = b1[t]; b2f[t] = b2[t]; }
  else if (t < 512) w1f[t - 128] = w1[t - 128];
  __syncthreads();

  const int lane = t & 63;
  const int wid  = t >> 6;
  const int rg   = wid & 1;   // row group (16 rows)
  const int wc   = wid >> 1;  // col group (32 cols)
  const int c    = lane & 15;
  const int g    = lane >> 4;

  // W2^T MFMA A-fragments: lane holds n = wc*32+nf*16+c, k = kk*32+g*8..+8
  short8 wfrag[2][4];
#pragma unroll
  for (int nf = 0; nf < 2; ++nf)
#pragma unroll
    for (int kk = 0; kk < 4; ++kk)
      wfrag[nf][kk] = *(const short8*)(w2t + (wc * 32 + nf * 16 + c) * 128 + kk * 32 + g * 8);

  f32x4 b2v0 = *(const f32x4*)&b2f[wc * 32 + g * 4];
  f32x4 b2v1 = *(const f32x4*)&b2f[wc * 32 + 16 + g * 4];

  for (int s = 0; s < 8; ++s) {
    int r  = bid * 256 + s * 32 + rg * 16 + c;
    int rl = r < E_KEEP ? r : E_KEEP - 1;
    int si = ei[rl];
    int di = ei[E_TOTAL_N + rl];
    float ax = pos[si * 3]     - pos[di * 3];
    float ay = pos[si * 3 + 1] - pos[di * 3 + 1];
    float an = sqrtf(ax * ax + ay * ay);

    f32x4 a0 = {}, a1 = {};
#pragma unroll
    for (int kk = 0; kk < 4; ++kk) {
      int k0 = kk * 32 + g * 8;
      f32x4 h0 = *(const f32x4*)&b1f[k0];
      f32x4 h1 = *(const f32x4*)&b1f[k0 + 4];
      h0 += ax * *(const f32x4*)&w1f[k0];
      h1 += ax * *(const f32x4*)&w1f[k0 + 4];
      h0 += ay * *(const f32x4*)&w1f[128 + k0];
      h1 += ay * *(const f32x4*)&w1f[128 + k0 + 4];
      h0 += an * *(const f32x4*)&w1f[256 + k0];
      h1 += an * *(const f32x4*)&w1f[256 + k0 + 4];
      short8 hf = mk_hfrag(h0, h1);
      a0 = __builtin_amdgcn_mfma_f32_16x16x32_bf16(wfrag[0][kk], hf, a0, 0, 0, 0);
      a1 = __builtin_amdgcn_mfma_f32_16x16x32_bf16(wfrag[1][kk], hf, a1, 0, 0, 0);
    }

    if (r < E_KEEP) {
      float* base = outp + EDGE_OUT_BASE + (long)r * 128 + wc * 32 + g * 4;
      *(f32x4*)(base)      = a0 + b2v0;
      *(f32x4*)(base + 16) = a1 + b2v1;
    }
  }
}

// ---------------- node path: attr = x row, K1 = 7 ----------------
__device__ __forceinline__ void run_nodes(
    const float* __restrict__ xin,
    const float* __restrict__ w1,
    const float* __restrict__ b1,
    const float* __restrict__ b2,
    const unsigned short* __restrict__ w2t,
    float* __restrict__ outp,
    int bid)
{
  __shared__ float w1fn[7 * 128];
  __shared__ float b1fn[128];
  __shared__ float b2fn[128];
  int t = threadIdx.x;
  if (t < 128) { b1fn[t] = b1[t]; b2fn[t] = b2[t]; }
  for (int i = t; i < 896; i += 512) w1fn[i] = w1[i];
  __syncthreads();

  const int lane = t & 63;
  const int wid  = t >> 6;
  const int rg   = wid & 1;
  const int wc   = wid >> 1;
  const int c    = lane & 15;
  const int g    = lane >> 4;

  short8 wfrag[2][4];
#pragma unroll
  for (int nf = 0; nf < 2; ++nf)
#pragma unroll
    for (int kk = 0; kk < 4; ++kk)
      wfrag[nf][kk] = *(const short8*)(w2t + (wc * 32 + nf * 16 + c) * 128 + kk * 32 + g * 8);

  f32x4 b2v0 = *(const f32x4*)&b2fn[wc * 32 + g * 4];
  f32x4 b2v1 = *(const f32x4*)&b2fn[wc * 32 + 16 + g * 4];

  for (int s = 0; s < 8; ++s) {
    int row0 = bid * 256 + s * 32 + rg * 16;
    if (row0 >= N_NODES) continue;
    int r  = row0 + c;
    int rl = r < N_NODES ? r : N_NODES - 1;

    float a[7];
#pragma unroll
    for (int cc = 0; cc < 7; ++cc) a[cc] = xin[rl * 7 + cc];

    f32x4 a0 = {}, a1 = {};
#pragma unroll
    for (int kk = 0; kk < 4; ++kk) {
      int k0 = kk * 32 + g * 8;
      f32x4 h0 = *(const f32x4*)&b1fn[k0];
      f32x4 h1 = *(const f32x4*)&b1fn[k0 + 4];
#pragma unroll
      for (int cc = 0; cc < 7; ++cc) {
        h0 += a[cc] * *(const f32x4*)&w1fn[cc * 128 + k0];
        h1 += a[cc] * *(const f32x4*)&w1fn[cc * 128 + k0 + 4];
      }
      short8 hf = mk_hfrag(h0, h1);
      a0 = __builtin_amdgcn_mfma_f32_16x16x32_bf16(wfrag[0][kk], hf, a0, 0, 0, 0);
      a1 = __builtin_amdgcn_mfma_f32_16x16x32_bf16(wfrag[1][kk], hf, a1, 0, 0, 0);
    }

    if (r < N_NODES) {
      float* base = outp + (long)r * 128 + wc * 32 + g * 4;
      *(f32x4*)(base)      = a0 + b2v0;
      *(f32x4*)(base + 16) = a1 + b2v1;
    }
  }
}

__global__ __launch_bounds__(512, 4) void encoder_kernel(
    const float* __restrict__ x,
    const float* __restrict__ pos,
    const int* __restrict__ ei,
    const float* __restrict__ nw1,
    const float* __restrict__ nb1,
    const float* __restrict__ nb2,
    const float* __restrict__ ew1,
    const float* __restrict__ eb1,
    const float* __restrict__ eb2,
    const unsigned short* __restrict__ ws,
    float* __restrict__ outp,
    int nodeBlocks)
{
  int bid = blockIdx.x;
  if (bid < nodeBlocks) {
    run_nodes(x, nw1, nb1, nb2, ws, outp, bid);
  } else {
    run_edges(pos, ei, ew1, eb1, eb2, ws + 16384, outp, bid - nodeBlocks);
  }
}

extern "C" void kernel_launch(void* const* d_in, const int* in_sizes, int n_in,
                              void* d_out, int out_size, void* d_ws, size_t ws_size,
                              hipStream_t stream) {
  const float* x   = (const float*)d_in[0];
  const float* pos = (const float*)d_in[1];
  const int*   ei  = (const int*)d_in[2];
  const float* nw1 = (const float*)d_in[3];
  const float* nb1 = (const float*)d_in[4];
  const float* nw2 = (const float*)d_in[5];
  const float* nb2 = (const float*)d_in[6];
  const float* ew1 = (const float*)d_in[7];
  const float* eb1 = (const float*)d_in[8];
  const float* ew2 = (const float*)d_in[9];
  const float* eb2 = (const float*)d_in[10];
  unsigned short* ws   = (unsigned short*)d_ws;
  float*          outp = (float*)d_out;

  transpose_w2<<<32, 256, 0, stream>>>(nw2, ew2, ws);

  int nodeBlocks = (N_NODES + 255) / 256;  // 391
  int edgeBlocks = (E_KEEP + 255) / 256;   // 3907
  encoder_kernel<<<nodeBlocks + edgeBlocks, 512, 0, stream>>>(
      x, pos, ei, nw1, nb1, nb2, ew1, eb1, eb2, ws, outp, nodeBlocks);
}

// Round 7
// 204.321 us; speedup vs baseline: 3.7710x; 3.7710x over previous
//
#include <hip/hip_runtime.h>

typedef short short8 __attribute__((ext_vector_type(8)));
typedef float f32x4 __attribute__((ext_vector_type(4)));
typedef unsigned int u32x4 __attribute__((ext_vector_type(4)));

#define N_NODES   100000
#define E_KEEP    1000000
#define E_TOTAL_N 1100000
#define EDGE_OUT_BASE 12800000L

__device__ __forceinline__ unsigned short f2bf(float f) {
  unsigned int u = __builtin_bit_cast(unsigned int, f);
  u += 0x7fffu + ((u >> 16) & 1u);   // round-to-nearest-even
  return (unsigned short)(u >> 16);
}

// relu both, pack 2 f32 -> u32 (lo in bits[15:0])
__device__ __forceinline__ unsigned int pack2(float lo, float hi) {
  return (unsigned int)f2bf(fmaxf(lo, 0.f)) |
         ((unsigned int)f2bf(fmaxf(hi, 0.f)) << 16);
}

// nw2/ew2 fp32 [128][128] -> bf16 W2^T in ws (node [0:16384], edge [16384:32768])
__global__ void transpose_w2(const float* __restrict__ nw2,
                             const float* __restrict__ ew2,
                             unsigned short* __restrict__ ws) {
  int idx = blockIdx.x * 256 + threadIdx.x;
  for (int i = idx; i < 32768; i += 8192) {
    int m = i >> 14;
    int w = i & 16383;
    int k = w >> 7;
    int n = w & 127;
    const float* src = m ? ew2 : nw2;
    ws[m * 16384 + n * 128 + k] = f2bf(src[w]);  // W2T[n][k] = W2[k][n]
  }
}

struct SmemLayout {
  float w1f[7 * 128];      // layer-1 weights (edges use first 3 rows)
  float b1f[128];
  float b2f[128];
  float attr[256 * 9];     // per-row attrs, stride 9 (coprime w/ 32 banks)
  char  h1[2][32 * 256];   // double-buffered bf16 h1 tile [32 rows][128 k], swizzled
};

// Block: 256 thr = 4 waves (rg = wid&1 row-group, wc = wid>>1 col-group of 64).
// Phase A: gather attrs once per row.  Phase B: layer-1 once per row -> LDS.
// Phase C: MFMA from LDS h1 (R2-proven fragment layout), direct stores.
template<bool IS_EDGE>
__device__ __forceinline__ void run_path(
    const float* __restrict__ src,   // pos (edges) or x (nodes)
    const int* __restrict__ ei,
    const float* __restrict__ w1,
    const float* __restrict__ b1,
    const float* __restrict__ b2,
    const unsigned short* __restrict__ w2t,
    float* __restrict__ outp, long out_base, int row_limit,
    int bid, SmemLayout& sm)
{
  constexpr int NA = IS_EDGE ? 3 : 7;
  const int t = threadIdx.x;

  // stage weights
  if (t < 128) { sm.b1f[t] = b1[t]; sm.b2f[t] = b2[t]; }
  for (int i = t; i < NA * 128; i += 256) sm.w1f[i] = w1[i];

  // ---- phase A: attrs for this block's 256 rows (1 row per thread) ----
  {
    int r  = bid * 256 + t;
    int rl = r < row_limit ? r : row_limit - 1;
    if (IS_EDGE) {
      int si = ei[rl];
      int di = ei[E_TOTAL_N + rl];
      float ax = src[si * 3]     - src[di * 3];
      float ay = src[si * 3 + 1] - src[di * 3 + 1];
      sm.attr[t * 9 + 0] = ax;
      sm.attr[t * 9 + 1] = ay;
      sm.attr[t * 9 + 2] = sqrtf(ax * ax + ay * ay);
    } else {
#pragma unroll
      for (int cc = 0; cc < 7; ++cc) sm.attr[t * 9 + cc] = src[rl * 7 + cc];
    }
  }

  const int lane = t & 63;
  const int wid  = t >> 6;
  const int rg   = wid & 1;
  const int wc   = wid >> 1;
  const int c    = lane & 15;
  const int g    = lane >> 4;

  // W2^T MFMA A-fragments (R2-proven): lane holds n = wc*64+nf*16+c, k = kk*32+g*8..+8
  short8 wfrag[4][4];
#pragma unroll
  for (int nf = 0; nf < 4; ++nf)
#pragma unroll
    for (int kk = 0; kk < 4; ++kk)
      wfrag[nf][kk] = *(const short8*)(w2t + (wc * 64 + nf * 16 + c) * 128 + kk * 32 + g * 8);

  __syncthreads();   // attrs + weights visible

  const int brow = t >> 3;          // phase-B tile-local row 0..31
  const int kc   = t & 7;           // phase-B k-chunk (16 k each)
  const int k0   = kc * 16;
  const unsigned int bswz = (unsigned int)((brow & 7) << 4);

  const int rrow = rg * 16 + c;     // phase-C tile-local row
  const unsigned int rswz = (unsigned int)((rrow & 7) << 4);

  for (int s = 0; s < 8; ++s) {
    char* h1 = sm.h1[s & 1];

    // ---- phase B: h1 for 32 rows x 128 k, computed ONCE, -> swizzled LDS ----
    {
      float a[NA];
#pragma unroll
      for (int cc = 0; cc < NA; ++cc) a[cc] = sm.attr[(s * 32 + brow) * 9 + cc];

      f32x4 h0 = *(const f32x4*)&sm.b1f[k0];
      f32x4 h1v = *(const f32x4*)&sm.b1f[k0 + 4];
      f32x4 h2 = *(const f32x4*)&sm.b1f[k0 + 8];
      f32x4 h3 = *(const f32x4*)&sm.b1f[k0 + 12];
#pragma unroll
      for (int cc = 0; cc < NA; ++cc) {
        h0  += a[cc] * *(const f32x4*)&sm.w1f[cc * 128 + k0];
        h1v += a[cc] * *(const f32x4*)&sm.w1f[cc * 128 + k0 + 4];
        h2  += a[cc] * *(const f32x4*)&sm.w1f[cc * 128 + k0 + 8];
        h3  += a[cc] * *(const f32x4*)&sm.w1f[cc * 128 + k0 + 12];
      }
      u32x4 dA, dB;
      dA[0] = pack2(h0[0], h0[1]);  dA[1] = pack2(h0[2], h0[3]);
      dA[2] = pack2(h1v[0], h1v[1]); dA[3] = pack2(h1v[2], h1v[3]);
      dB[0] = pack2(h2[0], h2[1]);  dB[1] = pack2(h2[2], h2[3]);
      dB[2] = pack2(h3[0], h3[1]);  dB[3] = pack2(h3[2], h3[3]);

      unsigned int base = (unsigned int)(brow * 256 + kc * 32);
      *(u32x4*)(h1 + (base ^ bswz))        = dA;
      *(u32x4*)(h1 + ((base + 16) ^ bswz)) = dB;
    }

    __syncthreads();   // h1 ready (also drains prev tile's phase-C reads)

    // ---- phase C: MFMA + direct store ----
    f32x4 acc0 = {}, acc1 = {}, acc2 = {}, acc3 = {};
#pragma unroll
    for (int kk = 0; kk < 4; ++kk) {
      unsigned int off = (unsigned int)(rrow * 256 + kk * 64 + g * 16);
      short8 hf = *(const short8*)(h1 + (off ^ rswz));
      acc0 = __builtin_amdgcn_mfma_f32_16x16x32_bf16(wfrag[0][kk], hf, acc0, 0, 0, 0);
      acc1 = __builtin_amdgcn_mfma_f32_16x16x32_bf16(wfrag[1][kk], hf, acc1, 0, 0, 0);
      acc2 = __builtin_amdgcn_mfma_f32_16x16x32_bf16(wfrag[2][kk], hf, acc2, 0, 0, 0);
      acc3 = __builtin_amdgcn_mfma_f32_16x16x32_bf16(wfrag[3][kk], hf, acc3, 0, 0, 0);
    }

    int r = bid * 256 + s * 32 + rrow;
    if (r < row_limit) {
      float* basep = outp + out_base + (long)r * 128;
      f32x4 av[4] = {acc0, acc1, acc2, acc3};
#pragma unroll
      for (int nf = 0; nf < 4; ++nf) {
        int col0 = wc * 64 + nf * 16 + g * 4;
        *(f32x4*)(basep + col0) = av[nf] + *(const f32x4*)&sm.b2f[col0];
      }
    }
  }
}

__global__ __launch_bounds__(256, 3) void encoder_kernel(
    const float* __restrict__ x,
    const float* __restrict__ pos,
    const int* __restrict__ ei,
    const float* __restrict__ nw1,
    const float* __restrict__ nb1,
    const float* __restrict__ nb2,
    const float* __restrict__ ew1,
    const float* __restrict__ eb1,
    const float* __restrict__ eb2,
    const unsigned short* __restrict__ ws,
    float* __restrict__ outp,
    int nodeBlocks)
{
  __shared__ SmemLayout sm;
  int bid = blockIdx.x;
  if (bid < nodeBlocks) {
    run_path<false>(x, nullptr, nw1, nb1, nb2, ws, outp, 0L, N_NODES, bid, sm);
  } else {
    run_path<true>(pos, ei, ew1, eb1, eb2, ws + 16384, outp, EDGE_OUT_BASE,
                   E_KEEP, bid - nodeBlocks, sm);
  }
}

extern "C" void kernel_launch(void* const* d_in, const int* in_sizes, int n_in,
                              void* d_out, int out_size, void* d_ws, size_t ws_size,
                              hipStream_t stream) {
  const float* x   = (const float*)d_in[0];
  const float* pos = (const float*)d_in[1];
  const int*   ei  = (const int*)d_in[2];
  const float* nw1 = (const float*)d_in[3];
  const float* nb1 = (const float*)d_in[4];
  const float* nw2 = (const float*)d_in[5];
  const float* nb2 = (const float*)d_in[6];
  const float* ew1 = (const float*)d_in[7];
  const float* eb1 = (const float*)d_in[8];
  const float* ew2 = (const float*)d_in[9];
  const float* eb2 = (const float*)d_in[10];
  unsigned short* ws   = (unsigned short*)d_ws;
  float*          outp = (float*)d_out;

  transpose_w2<<<32, 256, 0, stream>>>(nw2, ew2, ws);

  int nodeBlocks = (N_NODES + 255) / 256;  // 391
  int edgeBlocks = (E_KEEP + 255) / 256;   // 3907
  encoder_kernel<<<nodeBlocks + edgeBlocks, 256, 0, stream>>>(
      x, pos, ei, nw1, nb1, nb2, ew1, eb1, eb2, ws, outp, nodeBlocks);
}

// Round 8
// 175.066 us; speedup vs baseline: 4.4012x; 1.1671x over previous
//
#include <hip/hip_runtime.h>

typedef short short8 __attribute__((ext_vector_type(8)));
typedef float f32x4 __attribute__((ext_vector_type(4)));
typedef unsigned int u32x4 __attribute__((ext_vector_type(4)));

#define N_NODES   100000
#define E_KEEP    1000000
#define E_TOTAL_N 1100000
#define EDGE_OUT_BASE 12800000L

// h1 tile: 32 rows x 128 bf16, row stride padded 256 -> 272 bytes (odd quad
// count => consecutive lanes hit distinct bank-quads on both write and read).
#define H1_STRIDE 272

__device__ __forceinline__ unsigned short f2bf(float f) {
  unsigned int u = __builtin_bit_cast(unsigned int, f);
  u += 0x7fffu + ((u >> 16) & 1u);   // round-to-nearest-even
  return (unsigned short)(u >> 16);
}

// relu both, pack 2 f32 -> u32 (lo in bits[15:0])
__device__ __forceinline__ unsigned int pack2(float lo, float hi) {
  return (unsigned int)f2bf(fmaxf(lo, 0.f)) |
         ((unsigned int)f2bf(fmaxf(hi, 0.f)) << 16);
}

// nw2/ew2 fp32 [128][128] -> bf16 W2^T in ws (node [0:16384], edge [16384:32768])
__global__ void transpose_w2(const float* __restrict__ nw2,
                             const float* __restrict__ ew2,
                             unsigned short* __restrict__ ws) {
  int idx = blockIdx.x * 256 + threadIdx.x;
  for (int i = idx; i < 32768; i += 8192) {
    int m = i >> 14;
    int w = i & 16383;
    int k = w >> 7;
    int n = w & 127;
    const float* src = m ? ew2 : nw2;
    ws[m * 16384 + n * 128 + k] = f2bf(src[w]);  // W2T[n][k] = W2[k][n]
  }
}

struct SmemLayout {
  float w1f[7 * 128];      // layer-1 weights (edges use first 3 rows)
  float b1f[128];
  float b2f[128];
  float attr[256 * 7];     // per-row attrs, natural stride NA (3 or 7, coprime w/ 32)
  char  h1[2][32 * H1_STRIDE];  // double-buffered bf16 h1 tile
};

// Block: 256 thr = 4 waves (rg = wid&1 row-group, wc = wid>>1 col-group of 64).
// Phase A: gather attrs once per row.  Phase B: layer-1 once per row -> LDS
// (thread = (brow=t&31, kc=t>>5): writes conflict-free, w1 reads broadcast).
// Phase C: MFMA from padded LDS h1 (conflict-free reads), direct stores.
template<bool IS_EDGE>
__device__ __forceinline__ void run_path(
    const float* __restrict__ src,   // pos (edges) or x (nodes)
    const int* __restrict__ ei,
    const float* __restrict__ w1,
    const float* __restrict__ b1,
    const float* __restrict__ b2,
    const unsigned short* __restrict__ w2t,
    float* __restrict__ outp, long out_base, int row_limit,
    int bid, SmemLayout& sm)
{
  constexpr int NA = IS_EDGE ? 3 : 7;
  const int t = threadIdx.x;

  // stage weights
  if (t < 128) { sm.b1f[t] = b1[t]; sm.b2f[t] = b2[t]; }
  for (int i = t; i < NA * 128; i += 256) sm.w1f[i] = w1[i];

  // ---- phase A: attrs for this block's 256 rows (1 row per thread) ----
  {
    int r  = bid * 256 + t;
    int rl = r < row_limit ? r : row_limit - 1;
    if (IS_EDGE) {
      int si = ei[rl];
      int di = ei[E_TOTAL_N + rl];
      float ax = src[si * 3]     - src[di * 3];
      float ay = src[si * 3 + 1] - src[di * 3 + 1];
      sm.attr[t * 3 + 0] = ax;
      sm.attr[t * 3 + 1] = ay;
      sm.attr[t * 3 + 2] = sqrtf(ax * ax + ay * ay);
    } else {
#pragma unroll
      for (int cc = 0; cc < 7; ++cc) sm.attr[t * 7 + cc] = src[rl * 7 + cc];
    }
  }

  const int lane = t & 63;
  const int wid  = t >> 6;
  const int rg   = wid & 1;
  const int wc   = wid >> 1;
  const int c    = lane & 15;
  const int g    = lane >> 4;

  // W2^T MFMA A-fragments (R2-proven): lane holds n = wc*64+nf*16+c, k = kk*32+g*8..+8
  short8 wfrag[4][4];
#pragma unroll
  for (int nf = 0; nf < 4; ++nf)
#pragma unroll
    for (int kk = 0; kk < 4; ++kk)
      wfrag[nf][kk] = *(const short8*)(w2t + (wc * 64 + nf * 16 + c) * 128 + kk * 32 + g * 8);

  __syncthreads();   // attrs + weights visible

  // phase-B mapping: 32 rows x 8 k-chunks of 16 k.
  const int brow = t & 31;          // tile-local row
  const int kc   = t >> 5;          // k-chunk (16 k)
  const int k0   = kc * 16;

  const int rrow = rg * 16 + c;     // phase-C tile-local row

  for (int s = 0; s < 8; ++s) {
    char* h1 = sm.h1[s & 1];

    // ---- phase B: h1 for 32 rows x 128 k, computed ONCE, -> padded LDS ----
    {
      float a[NA];
#pragma unroll
      for (int cc = 0; cc < NA; ++cc) a[cc] = sm.attr[(s * 32 + brow) * NA + cc];

      f32x4 h0 = *(const f32x4*)&sm.b1f[k0];
      f32x4 h1v = *(const f32x4*)&sm.b1f[k0 + 4];
      f32x4 h2 = *(const f32x4*)&sm.b1f[k0 + 8];
      f32x4 h3 = *(const f32x4*)&sm.b1f[k0 + 12];
#pragma unroll
      for (int cc = 0; cc < NA; ++cc) {
        h0  += a[cc] * *(const f32x4*)&sm.w1f[cc * 128 + k0];
        h1v += a[cc] * *(const f32x4*)&sm.w1f[cc * 128 + k0 + 4];
        h2  += a[cc] * *(const f32x4*)&sm.w1f[cc * 128 + k0 + 8];
        h3  += a[cc] * *(const f32x4*)&sm.w1f[cc * 128 + k0 + 12];
      }
      u32x4 dA, dB;
      dA[0] = pack2(h0[0], h0[1]);  dA[1] = pack2(h0[2], h0[3]);
      dA[2] = pack2(h1v[0], h1v[1]); dA[3] = pack2(h1v[2], h1v[3]);
      dB[0] = pack2(h2[0], h2[1]);  dB[1] = pack2(h2[2], h2[3]);
      dB[2] = pack2(h3[0], h3[1]);  dB[3] = pack2(h3[2], h3[3]);

      char* wp = h1 + brow * H1_STRIDE + kc * 32;
      *(u32x4*)(wp)      = dA;
      *(u32x4*)(wp + 16) = dB;
    }

    __syncthreads();   // h1 ready (prev tile's phase-C reads already drained)

    // ---- phase C: MFMA + direct store ----
    f32x4 acc0 = {}, acc1 = {}, acc2 = {}, acc3 = {};
#pragma unroll
    for (int kk = 0; kk < 4; ++kk) {
      short8 hf = *(const short8*)(h1 + rrow * H1_STRIDE + kk * 64 + g * 16);
      acc0 = __builtin_amdgcn_mfma_f32_16x16x32_bf16(wfrag[0][kk], hf, acc0, 0, 0, 0);
      acc1 = __builtin_amdgcn_mfma_f32_16x16x32_bf16(wfrag[1][kk], hf, acc1, 0, 0, 0);
      acc2 = __builtin_amdgcn_mfma_f32_16x16x32_bf16(wfrag[2][kk], hf, acc2, 0, 0, 0);
      acc3 = __builtin_amdgcn_mfma_f32_16x16x32_bf16(wfrag[3][kk], hf, acc3, 0, 0, 0);
    }

    int r = bid * 256 + s * 32 + rrow;
    if (r < row_limit) {
      float* basep = outp + out_base + (long)r * 128;
      f32x4 av[4] = {acc0, acc1, acc2, acc3};
#pragma unroll
      for (int nf = 0; nf < 4; ++nf) {
        int col0 = wc * 64 + nf * 16 + g * 4;
        *(f32x4*)(basep + col0) = av[nf] + *(const f32x4*)&sm.b2f[col0];
      }
    }
  }
}

__global__ __launch_bounds__(256, 3) void encoder_kernel(
    const float* __restrict__ x,
    const float* __restrict__ pos,
    const int* __restrict__ ei,
    const float* __restrict__ nw1,
    const float* __restrict__ nb1,
    const float* __restrict__ nb2,
    const float* __restrict__ ew1,
    const float* __restrict__ eb1,
    const float* __restrict__ eb2,
    const unsigned short* __restrict__ ws,
    float* __restrict__ outp,
    int nodeBlocks)
{
  __shared__ SmemLayout sm;
  int bid = blockIdx.x;
  if (bid < nodeBlocks) {
    run_path<false>(x, nullptr, nw1, nb1, nb2, ws, outp, 0L, N_NODES, bid, sm);
  } else {
    run_path<true>(pos, ei, ew1, eb1, eb2, ws + 16384, outp, EDGE_OUT_BASE,
                   E_KEEP, bid - nodeBlocks, sm);
  }
}

extern "C" void kernel_launch(void* const* d_in, const int* in_sizes, int n_in,
                              void* d_out, int out_size, void* d_ws, size_t ws_size,
                              hipStream_t stream) {
  const float* x   = (const float*)d_in[0];
  const float* pos = (const float*)d_in[1];
  const int*   ei  = (const int*)d_in[2];
  const float* nw1 = (const float*)d_in[3];
  const float* nb1 = (const float*)d_in[4];
  const float* nw2 = (const float*)d_in[5];
  const float* nb2 = (const float*)d_in[6];
  const float* ew1 = (const float*)d_in[7];
  const float* eb1 = (const float*)d_in[8];
  const float* ew2 = (const float*)d_in[9];
  const float* eb2 = (const float*)d_in[10];
  unsigned short* ws   = (unsigned short*)d_ws;
  float*          outp = (float*)d_out;

  transpose_w2<<<32, 256, 0, stream>>>(nw2, ew2, ws);

  int nodeBlocks = (N_NODES + 255) / 256;  // 391
  int edgeBlocks = (E_KEEP + 255) / 256;   // 3907
  encoder_kernel<<<nodeBlocks + edgeBlocks, 256, 0, stream>>>(
      x, pos, ei, nw1, nb1, nb2, ew1, eb1, eb2, ws, outp, nodeBlocks);
}